// Round 2
// baseline (508.621 us; speedup 1.0000x reference)
//
#include <hip/hip_runtime.h>
#include <hip/hip_bf16.h>
#include <float.h>

#define NB 4
#define SEQ 1024
#define DIM 768
#define NH 12
#define HD 64
#define SCALE_F 0.125f

// ---------------------------------------------------------------------------
// Mask normalization: the harness may deliver the bool mask as int32 (0/1)
// or raw uint8. Detect by reading the first 4096 bytes as u32: the mask's
// long runs of `true` give 0x01010101 (>1) iff stored as uint8.
// Output: mnorm[4096] int32 (0/1).
// ---------------------------------------------------------------------------
__global__ void mask_norm_kernel(const void* __restrict__ mask_raw,
                                 int* __restrict__ mnorm) {
    __shared__ int is_u8;
    const int tid = threadIdx.x;
    if (tid == 0) is_u8 = 0;
    __syncthreads();
    const unsigned int* u32 = (const unsigned int*)mask_raw;
    int bad = 0;
    for (int i = tid; i < (NB * SEQ) / 4; i += blockDim.x)
        if (u32[i] > 1u) bad = 1;          // safe: 4KB <= either storage size
    if (bad) atomicOr(&is_u8, 1);
    __syncthreads();
    const int u8mode = is_u8;
    const unsigned char* u8 = (const unsigned char*)mask_raw;
    const int* i32 = (const int*)mask_raw;
    for (int i = tid; i < NB * SEQ; i += blockDim.x)
        mnorm[i] = u8mode ? (u8[i] != 0) : (i32[i] != 0);
}

// ---------------------------------------------------------------------------
// QKV GEMM: C[m,o] = sum_k X[m,k] * Wqkv[o,k];  M=4096, O=2304, K=768.
// 64x64 tile, BK=16, 256 threads, 4x4 per thread, fp32.
// Epilogue scatters into Q/K/V [B*H, N, D] buffers.
// ---------------------------------------------------------------------------
__global__ __launch_bounds__(256) void qkv_gemm_kernel(
    const float* __restrict__ X, const float* __restrict__ Wqkv,
    float* __restrict__ Qb, float* __restrict__ Kb, float* __restrict__ Vb) {
    const int m0 = blockIdx.y * 64;
    const int o0 = blockIdx.x * 64;
    __shared__ float As[16][68];  // [k][m]
    __shared__ float Bs[16][68];  // [k][o]
    const int tid = threadIdx.x;
    const int tx = tid & 15, ty = tid >> 4;
    // loader coords: one float4 of A and one of B per thread per K-tile
    const int lrow = tid >> 2;    // 0..63
    const int lc4  = tid & 3;     // 0..3  -> cols lc4*4 .. +3

    float acc[4][4] = {};
    for (int k0 = 0; k0 < DIM; k0 += 16) {
        __syncthreads();
        float4 av = *(const float4*)(X + (size_t)(m0 + lrow) * DIM + k0 + lc4 * 4);
        float4 bv = *(const float4*)(Wqkv + (size_t)(o0 + lrow) * DIM + k0 + lc4 * 4);
        As[lc4 * 4 + 0][lrow] = av.x; As[lc4 * 4 + 1][lrow] = av.y;
        As[lc4 * 4 + 2][lrow] = av.z; As[lc4 * 4 + 3][lrow] = av.w;
        Bs[lc4 * 4 + 0][lrow] = bv.x; Bs[lc4 * 4 + 1][lrow] = bv.y;
        Bs[lc4 * 4 + 2][lrow] = bv.z; Bs[lc4 * 4 + 3][lrow] = bv.w;
        __syncthreads();
#pragma unroll
        for (int k = 0; k < 16; ++k) {
            float a[4], b[4];
#pragma unroll
            for (int i = 0; i < 4; ++i) a[i] = As[k][ty * 4 + i];
#pragma unroll
            for (int j = 0; j < 4; ++j) b[j] = Bs[k][tx * 4 + j];
#pragma unroll
            for (int i = 0; i < 4; ++i)
#pragma unroll
                for (int j = 0; j < 4; ++j) acc[i][j] += a[i] * b[j];
        }
    }
    // epilogue: o-tile bx -> (s = bx/12, h = bx%12), cols are d = tx*4+j
    const int bx = blockIdx.x;
    const int s = bx / 12, h = bx % 12;
    float* dst = (s == 0) ? Qb : (s == 1 ? Kb : Vb);
#pragma unroll
    for (int i = 0; i < 4; ++i) {
        const int m = m0 + ty * 4 + i;
        const int b = m >> 10, n = m & 1023;
        float* drow = dst + (((size_t)(b * NH + h)) * SEQ + n) * HD;
#pragma unroll
        for (int j = 0; j < 4; ++j) drow[tx * 4 + j] = acc[i][j];
    }
}

// ---------------------------------------------------------------------------
// Flash-style masked attention, fp32. Block: (query tile of 64) x (b,h).
// 256 threads as 16x16; thread computes 4 rows x 4 cols of S and O.
// pair_mask==false -> score = -FLT_MAX (matches reference exactly, incl.
// uniform softmax over fully-masked rows).
// ---------------------------------------------------------------------------
__global__ __launch_bounds__(256) void attn_kernel(
    const float* __restrict__ Qb, const float* __restrict__ Kb,
    const float* __restrict__ Vb, const int* __restrict__ mnorm,
    float* __restrict__ Ob) {
    const int bh = blockIdx.y;            // 0..47
    const int b = bh / NH;
    const int q0 = blockIdx.x * 64;
    const float* Qp = Qb + (size_t)bh * SEQ * HD;
    const float* Kp = Kb + (size_t)bh * SEQ * HD;
    const float* Vp = Vb + (size_t)bh * SEQ * HD;

    __shared__ float Qs[64][68];  // [d][r]   (transposed)
    __shared__ float Ks[64][68];  // [d][kc]  (transposed)
    __shared__ float Vs[64][68];  // [kc][dc]
    __shared__ float Ss[64][68];  // [kc][r]  (P transposed)
    __shared__ int mks[64];

    const int tid = threadIdx.x;
    const int tx = tid & 15, ty = tid >> 4;

    // load Q tile (transposed into Qs[d][r])
#pragma unroll
    for (int i = 0; i < 4; ++i) {
        int idx = tid + i * 256;          // 0..1023
        int r = idx >> 4, c4 = idx & 15;
        float4 qv = *(const float4*)(Qp + (size_t)(q0 + r) * HD + c4 * 4);
        Qs[c4 * 4 + 0][r] = qv.x; Qs[c4 * 4 + 1][r] = qv.y;
        Qs[c4 * 4 + 2][r] = qv.z; Qs[c4 * 4 + 3][r] = qv.w;
    }
    int mq[4];
#pragma unroll
    for (int i = 0; i < 4; ++i) mq[i] = mnorm[b * SEQ + q0 + ty * 4 + i];

    float m_run[4], l_run[4], o_acc[4][4];
#pragma unroll
    for (int i = 0; i < 4; ++i) {
        m_run[i] = -FLT_MAX; l_run[i] = 0.0f;
#pragma unroll
        for (int j = 0; j < 4; ++j) o_acc[i][j] = 0.0f;
    }

    for (int k0 = 0; k0 < SEQ; k0 += 64) {
        __syncthreads();   // previous iteration's reads of Ks/Vs/Ss done
#pragma unroll
        for (int i = 0; i < 4; ++i) {
            int idx = tid + i * 256;
            int r = idx >> 4, c4 = idx & 15;
            float4 kv = *(const float4*)(Kp + (size_t)(k0 + r) * HD + c4 * 4);
            Ks[c4 * 4 + 0][r] = kv.x; Ks[c4 * 4 + 1][r] = kv.y;
            Ks[c4 * 4 + 2][r] = kv.z; Ks[c4 * 4 + 3][r] = kv.w;
            float4 vv = *(const float4*)(Vp + (size_t)(k0 + r) * HD + c4 * 4);
            *(float4*)(&Vs[r][c4 * 4]) = vv;
        }
        if (tid < 64) mks[tid] = mnorm[b * SEQ + k0 + tid];
        __syncthreads();

        // S = Q K^T for this thread's 4x4
        float s[4][4] = {};
#pragma unroll 16
        for (int d = 0; d < 64; ++d) {
            float a[4], kk[4];
#pragma unroll
            for (int i = 0; i < 4; ++i) a[i] = Qs[d][ty * 4 + i];
#pragma unroll
            for (int j = 0; j < 4; ++j) kk[j] = Ks[d][tx * 4 + j];
#pragma unroll
            for (int i = 0; i < 4; ++i)
#pragma unroll
                for (int j = 0; j < 4; ++j) s[i][j] += a[i] * kk[j];
        }
        int mk[4];
#pragma unroll
        for (int j = 0; j < 4; ++j) mk[j] = mks[tx * 4 + j];
#pragma unroll
        for (int i = 0; i < 4; ++i)
#pragma unroll
            for (int j = 0; j < 4; ++j)
                s[i][j] = (mq[i] && mk[j]) ? s[i][j] * SCALE_F : -FLT_MAX;

        // online softmax update (row groups of 16 lanes share ty)
#pragma unroll
        for (int i = 0; i < 4; ++i) {
            float pm = fmaxf(fmaxf(s[i][0], s[i][1]), fmaxf(s[i][2], s[i][3]));
            pm = fmaxf(pm, __shfl_xor(pm, 1));
            pm = fmaxf(pm, __shfl_xor(pm, 2));
            pm = fmaxf(pm, __shfl_xor(pm, 4));
            pm = fmaxf(pm, __shfl_xor(pm, 8));
            float m_new = fmaxf(m_run[i], pm);
            float alpha = __expf(m_run[i] - m_new);
            float rs = 0.0f;
#pragma unroll
            for (int j = 0; j < 4; ++j) {
                float p = __expf(s[i][j] - m_new);
                s[i][j] = p;
                rs += p;
            }
            rs += __shfl_xor(rs, 1);
            rs += __shfl_xor(rs, 2);
            rs += __shfl_xor(rs, 4);
            rs += __shfl_xor(rs, 8);
            l_run[i] = l_run[i] * alpha + rs;
            m_run[i] = m_new;
#pragma unroll
            for (int j = 0; j < 4; ++j) o_acc[i][j] *= alpha;
        }
        // publish P (transposed: Ss[kc][r])
#pragma unroll
        for (int i = 0; i < 4; ++i)
#pragma unroll
            for (int j = 0; j < 4; ++j)
                Ss[tx * 4 + j][ty * 4 + i] = s[i][j];
        __syncthreads();

        // O += P V
#pragma unroll 16
        for (int kc = 0; kc < 64; ++kc) {
            float p[4], vv[4];
#pragma unroll
            for (int i = 0; i < 4; ++i) p[i] = Ss[kc][ty * 4 + i];
#pragma unroll
            for (int j = 0; j < 4; ++j) vv[j] = Vs[kc][tx * 4 + j];
#pragma unroll
            for (int i = 0; i < 4; ++i)
#pragma unroll
                for (int j = 0; j < 4; ++j) o_acc[i][j] += p[i] * vv[j];
        }
    }
    // epilogue
#pragma unroll
    for (int i = 0; i < 4; ++i) {
        float inv = 1.0f / l_run[i];
        float* orow = Ob + ((size_t)bh * SEQ + (q0 + ty * 4 + i)) * HD;
#pragma unroll
        for (int j = 0; j < 4; ++j) orow[tx * 4 + j] = o_acc[i][j] * inv;
    }
}

// ---------------------------------------------------------------------------
// Output projection: out[m,o] = sum_c AO2[m,c] * Wp[o,c] + bp[o], fp32 out.
// AO2[m, c=h*64+d] gathered from AO[(b*12+h), n, d]. BK=16 stays within one h.
// ---------------------------------------------------------------------------
__global__ __launch_bounds__(256) void proj_gemm_kernel(
    const float* __restrict__ AO, const float* __restrict__ Wp,
    const float* __restrict__ bp, float* __restrict__ out) {
    const int m0 = blockIdx.y * 64;
    const int o0 = blockIdx.x * 64;
    __shared__ float As[16][68];
    __shared__ float Bs[16][68];
    const int tid = threadIdx.x;
    const int tx = tid & 15, ty = tid >> 4;
    const int lrow = tid >> 2, lc4 = tid & 3;
    const int lm = m0 + lrow;
    const int lb = lm >> 10, ln = lm & 1023;

    float acc[4][4] = {};
    for (int k0 = 0; k0 < DIM; k0 += 16) {
        const int h = k0 >> 6, dbase = k0 & 63;
        __syncthreads();
        float4 av = *(const float4*)(AO + (((size_t)(lb * NH + h)) * SEQ + ln) * HD
                                        + dbase + lc4 * 4);
        float4 bv = *(const float4*)(Wp + (size_t)(o0 + lrow) * DIM + k0 + lc4 * 4);
        As[lc4 * 4 + 0][lrow] = av.x; As[lc4 * 4 + 1][lrow] = av.y;
        As[lc4 * 4 + 2][lrow] = av.z; As[lc4 * 4 + 3][lrow] = av.w;
        Bs[lc4 * 4 + 0][lrow] = bv.x; Bs[lc4 * 4 + 1][lrow] = bv.y;
        Bs[lc4 * 4 + 2][lrow] = bv.z; Bs[lc4 * 4 + 3][lrow] = bv.w;
        __syncthreads();
#pragma unroll
        for (int k = 0; k < 16; ++k) {
            float a[4], b[4];
#pragma unroll
            for (int i = 0; i < 4; ++i) a[i] = As[k][ty * 4 + i];
#pragma unroll
            for (int j = 0; j < 4; ++j) b[j] = Bs[k][tx * 4 + j];
#pragma unroll
            for (int i = 0; i < 4; ++i)
#pragma unroll
                for (int j = 0; j < 4; ++j) acc[i][j] += a[i] * b[j];
        }
    }
#pragma unroll
    for (int i = 0; i < 4; ++i) {
        const int m = m0 + ty * 4 + i;
#pragma unroll
        for (int j = 0; j < 4; ++j) {
            const int o = o0 + tx * 4 + j;
            out[(size_t)m * DIM + o] = acc[i][j] + bp[o];
        }
    }
}

// ---------------------------------------------------------------------------
extern "C" void kernel_launch(void* const* d_in, const int* in_sizes, int n_in,
                              void* d_out, int out_size, void* d_ws, size_t ws_size,
                              hipStream_t stream) {
    const float* x      = (const float*)d_in[0];
    const void*  mask   = d_in[1];
    const float* w_qkv  = (const float*)d_in[2];
    const float* w_proj = (const float*)d_in[3];
    const float* b_proj = (const float*)d_in[4];
    float* out          = (float*)d_out;

    // workspace carve
    char* w = (char*)d_ws;
    int* mnorm = (int*)w;                 w += ((NB * SEQ * sizeof(int)) + 255) & ~255;
    const size_t bhnd = (size_t)NB * NH * SEQ * HD;   // 3,145,728
    float* Qb = (float*)w;                w += bhnd * sizeof(float);
    float* Kb = (float*)w;                w += bhnd * sizeof(float);
    float* Vb = (float*)w;                w += bhnd * sizeof(float);
    float* Ob = (float*)w;                w += bhnd * sizeof(float);

    mask_norm_kernel<<<1, 256, 0, stream>>>(mask, mnorm);
    qkv_gemm_kernel<<<dim3(36, 64), 256, 0, stream>>>(x, w_qkv, Qb, Kb, Vb);
    attn_kernel<<<dim3(SEQ / 64, NB * NH), 256, 0, stream>>>(Qb, Kb, Vb, mnorm, Ob);
    proj_gemm_kernel<<<dim3(12, 64), 256, 0, stream>>>(Ob, w_proj, b_proj, out);
}

// Round 3
// 131.370 us; speedup vs baseline: 3.8717x; 3.8717x over previous
//
#include <hip/hip_runtime.h>
#include <hip/hip_fp16.h>
#include <float.h>

typedef _Float16 f16;
typedef __attribute__((ext_vector_type(4))) _Float16 f16x4;
typedef __attribute__((ext_vector_type(8))) _Float16 f16x8;
typedef __attribute__((ext_vector_type(4))) float f32x4;

#define NB 4
#define SEQ 1024
#define DIM 768
#define NH 12
#define HD 64
#define SCALE_F 0.125f

// ---------------------------------------------------------------------------
// Mask normalization (proven in round 2): int32-or-uint8 autodetect.
// ---------------------------------------------------------------------------
__global__ void mask_norm_kernel(const void* __restrict__ mask_raw,
                                 int* __restrict__ mnorm) {
    __shared__ int is_u8;
    const int tid = threadIdx.x;
    if (tid == 0) is_u8 = 0;
    __syncthreads();
    const unsigned int* u32 = (const unsigned int*)mask_raw;
    int bad = 0;
    for (int i = tid; i < (NB * SEQ) / 4; i += blockDim.x)
        if (u32[i] > 1u) bad = 1;
    if (bad) atomicOr(&is_u8, 1);
    __syncthreads();
    const int u8mode = is_u8;
    const unsigned char* u8 = (const unsigned char*)mask_raw;
    const int* i32 = (const int*)mask_raw;
    for (int i = tid; i < NB * SEQ; i += blockDim.x)
        mnorm[i] = u8mode ? (u8[i] != 0) : (i32[i] != 0);
}

// ---------------------------------------------------------------------------
// fp32 -> fp16 convert for X, w_qkv, w_proj (one fused launch).
// ---------------------------------------------------------------------------
__global__ __launch_bounds__(256) void cvt_kernel(
    const float* __restrict__ X, const float* __restrict__ W1,
    const float* __restrict__ W2, f16* __restrict__ Xh,
    f16* __restrict__ W1h, f16* __restrict__ W2h) {
    const int A4 = (NB * SEQ * DIM) / 4;   // 786432
    const int B4 = (3 * DIM * DIM) / 4;    // 442368
    const int C4 = (DIM * DIM) / 4;        // 147456
    int i = blockIdx.x * 256 + threadIdx.x;
    const float* s; f16* d; int j;
    if (i < A4)                { s = X;  d = Xh;  j = i; }
    else if (i < A4 + B4)      { s = W1; d = W1h; j = i - A4; }
    else if (i < A4 + B4 + C4) { s = W2; d = W2h; j = i - A4 - B4; }
    else return;
    float4 v = ((const float4*)s)[j];
    f16x4 h;
    h[0] = (f16)v.x; h[1] = (f16)v.y; h[2] = (f16)v.z; h[3] = (f16)v.w;
    *(f16x4*)(d + 4 * (size_t)j) = h;
}

// ---------------------------------------------------------------------------
// QKV GEMM, fp16 MFMA 16x16x32. C[m,o] = sum_k Xh[m,k]*Wh[o,k].
// 128x128 tile, BK=32, 4 waves (2x2), each wave 64x64 (4x4 frags).
// Epilogue: Q,K -> [bh][n][d] fp16; V -> transposed [bh][d][n] fp16.
// ---------------------------------------------------------------------------
__global__ __launch_bounds__(256) void qkv_gemm_f16(
    const f16* __restrict__ Xh, const f16* __restrict__ Wh,
    f16* __restrict__ Qh, f16* __restrict__ Kh, f16* __restrict__ Vth) {
    __shared__ f16 Asm[128][40];   // [m][k], +16B pad
    __shared__ f16 Bsm[128][40];   // [o][k]
    const int tid = threadIdx.x;
    const int l = tid & 63, w = tid >> 6;
    const int lo = l & 15, hi = l >> 4;
    const int wm = w >> 1, wn = w & 1;
    const int m0 = blockIdx.y * 128, o0 = blockIdx.x * 128;

    f32x4 acc[4][4];
#pragma unroll
    for (int i = 0; i < 4; ++i)
#pragma unroll
        for (int j = 0; j < 4; ++j) { f32x4 z = {0.f, 0.f, 0.f, 0.f}; acc[i][j] = z; }

    const int rr = tid >> 1, cs = (tid & 1) * 16;   // 128 rows x 32 cols staging
    for (int k0 = 0; k0 < DIM; k0 += 32) {
        __syncthreads();
        f16x8 av0 = *(const f16x8*)(Xh + (size_t)(m0 + rr) * DIM + k0 + cs);
        f16x8 av1 = *(const f16x8*)(Xh + (size_t)(m0 + rr) * DIM + k0 + cs + 8);
        f16x8 bv0 = *(const f16x8*)(Wh + (size_t)(o0 + rr) * DIM + k0 + cs);
        f16x8 bv1 = *(const f16x8*)(Wh + (size_t)(o0 + rr) * DIM + k0 + cs + 8);
        *(f16x8*)(&Asm[rr][cs])     = av0;
        *(f16x8*)(&Asm[rr][cs + 8]) = av1;
        *(f16x8*)(&Bsm[rr][cs])     = bv0;
        *(f16x8*)(&Bsm[rr][cs + 8]) = bv1;
        __syncthreads();
        f16x8 af[4], bf[4];
#pragma unroll
        for (int i = 0; i < 4; ++i)
            af[i] = *(const f16x8*)(&Asm[wm * 64 + i * 16 + lo][hi * 8]);
#pragma unroll
        for (int j = 0; j < 4; ++j)
            bf[j] = *(const f16x8*)(&Bsm[wn * 64 + j * 16 + lo][hi * 8]);
#pragma unroll
        for (int i = 0; i < 4; ++i)
#pragma unroll
            for (int j = 0; j < 4; ++j)
                acc[i][j] = __builtin_amdgcn_mfma_f32_16x16x32_f16(af[i], bf[j], acc[i][j], 0, 0, 0);
    }

    // epilogue
    const int oo = o0 + wn * 64;            // 64-aligned -> single (s,h)
    const int s = oo / DIM;                 // 0=Q,1=K,2=V
    const int hh = (oo % DIM) / HD;
    const int b = m0 >> 10;
    const int nbase = (m0 & 1023) + wm * 64;
    if (s < 2) {
        f16* dst = (s == 0) ? Qh : Kh;
        f16* base = dst + ((size_t)(b * NH + hh)) * SEQ * HD;
#pragma unroll
        for (int i = 0; i < 4; ++i)
#pragma unroll
            for (int r = 0; r < 4; ++r) {
                const int n = nbase + i * 16 + hi * 4 + r;
#pragma unroll
                for (int j = 0; j < 4; ++j)
                    base[(size_t)n * HD + j * 16 + lo] = (f16)acc[i][j][r];
            }
    } else {
        f16* base = Vth + ((size_t)(b * NH + hh)) * HD * SEQ;
#pragma unroll
        for (int i = 0; i < 4; ++i) {
            const int n4 = nbase + i * 16 + hi * 4;
#pragma unroll
            for (int j = 0; j < 4; ++j) {
                const int d = j * 16 + lo;
                f16x4 pv;
#pragma unroll
                for (int r = 0; r < 4; ++r) pv[r] = (f16)acc[i][j][r];
                *(f16x4*)(base + (size_t)d * SEQ + n4) = pv;
            }
        }
    }
}

// ---------------------------------------------------------------------------
// Flash attention, fp16 MFMA. Block = 64 q-rows x (b,h); 4 waves, each owns
// 16 q-rows. KV tiles of 64. Ps is per-wave private (no extra barriers).
// ---------------------------------------------------------------------------
__global__ __launch_bounds__(256) void attn_f16(
    const f16* __restrict__ Qh, const f16* __restrict__ Kh,
    const f16* __restrict__ Vth, const int* __restrict__ mnorm,
    f16* __restrict__ Oh) {
    const int bh = blockIdx.y, b = bh / NH, hh = bh % NH;
    const int q0 = blockIdx.x * 64;
    const int tid = threadIdx.x;
    const int l = tid & 63, w = tid >> 6;
    const int lo = l & 15, hi = l >> 4;

    __shared__ f16 Ks[64][72];        // [kv][d]
    __shared__ f16 Vs[64][72];        // [d][kv]  (from transposed V)
    __shared__ f16 Ps[4][16][72];     // per-wave P tile [qr][kv]
    __shared__ int mks[64];

    const f16* Qp = Qh + (size_t)bh * SEQ * HD;
    const f16* Kp = Kh + (size_t)bh * SEQ * HD;
    const f16* Vp = Vth + (size_t)bh * HD * SEQ;

    // Q A-frags held in registers for the whole kernel
    f16x8 qa[2];
#pragma unroll
    for (int kk = 0; kk < 2; ++kk)
        qa[kk] = *(const f16x8*)(Qp + (size_t)(q0 + w * 16 + lo) * HD + kk * 32 + hi * 8);
    int mq[4];
#pragma unroll
    for (int r = 0; r < 4; ++r) mq[r] = mnorm[b * SEQ + q0 + w * 16 + hi * 4 + r];

    float m_run[4], l_run[4];
    f32x4 oacc[4];
#pragma unroll
    for (int r = 0; r < 4; ++r) { m_run[r] = -FLT_MAX; l_run[r] = 0.f; }
#pragma unroll
    for (int n = 0; n < 4; ++n) { f32x4 z = {0.f, 0.f, 0.f, 0.f}; oacc[n] = z; }

    const int sr = tid >> 2, sc = (tid & 3) * 16;   // staging: 64 rows x 64 cols
    for (int kv0 = 0; kv0 < SEQ; kv0 += 64) {
        __syncthreads();
        {
            f16x8 k0v = *(const f16x8*)(Kp + (size_t)(kv0 + sr) * HD + sc);
            f16x8 k1v = *(const f16x8*)(Kp + (size_t)(kv0 + sr) * HD + sc + 8);
            f16x8 v0v = *(const f16x8*)(Vp + (size_t)sr * SEQ + kv0 + sc);
            f16x8 v1v = *(const f16x8*)(Vp + (size_t)sr * SEQ + kv0 + sc + 8);
            *(f16x8*)(&Ks[sr][sc])     = k0v;
            *(f16x8*)(&Ks[sr][sc + 8]) = k1v;
            *(f16x8*)(&Vs[sr][sc])     = v0v;
            *(f16x8*)(&Vs[sr][sc + 8]) = v1v;
            if (tid < 64) mks[tid] = mnorm[b * SEQ + kv0 + tid];
        }
        __syncthreads();

        // S = Q K^T  (frag f covers kv cols f*16..f*16+15)
        f32x4 sf[4];
#pragma unroll
        for (int f = 0; f < 4; ++f) { f32x4 z = {0.f, 0.f, 0.f, 0.f}; sf[f] = z; }
#pragma unroll
        for (int f = 0; f < 4; ++f)
#pragma unroll
            for (int kk = 0; kk < 2; ++kk) {
                f16x8 kf = *(const f16x8*)(&Ks[f * 16 + lo][kk * 32 + hi * 8]);
                sf[f] = __builtin_amdgcn_mfma_f32_16x16x32_f16(qa[kk], kf, sf[f], 0, 0, 0);
            }
        // scale + mask
        int mk[4];
#pragma unroll
        for (int f = 0; f < 4; ++f) mk[f] = mks[f * 16 + lo];
#pragma unroll
        for (int f = 0; f < 4; ++f)
#pragma unroll
            for (int r = 0; r < 4; ++r)
                sf[f][r] = (mq[r] && mk[f]) ? sf[f][r] * SCALE_F : -FLT_MAX;

        // online softmax (row r lives on the 16 lanes sharing hi)
        float alpha[4];
#pragma unroll
        for (int r = 0; r < 4; ++r) {
            float pm = fmaxf(fmaxf(sf[0][r], sf[1][r]), fmaxf(sf[2][r], sf[3][r]));
            pm = fmaxf(pm, __shfl_xor(pm, 1));
            pm = fmaxf(pm, __shfl_xor(pm, 2));
            pm = fmaxf(pm, __shfl_xor(pm, 4));
            pm = fmaxf(pm, __shfl_xor(pm, 8));
            float mn = fmaxf(m_run[r], pm);
            alpha[r] = __expf(m_run[r] - mn);
            m_run[r] = mn;
            float rs = 0.f;
#pragma unroll
            for (int f = 0; f < 4; ++f) {
                float p = __expf(sf[f][r] - mn);
                sf[f][r] = p;
                rs += p;
            }
            rs += __shfl_xor(rs, 1);
            rs += __shfl_xor(rs, 2);
            rs += __shfl_xor(rs, 4);
            rs += __shfl_xor(rs, 8);
            l_run[r] = l_run[r] * alpha[r] + rs;
        }
        // P -> per-wave LDS (fp16)
#pragma unroll
        for (int f = 0; f < 4; ++f)
#pragma unroll
            for (int r = 0; r < 4; ++r)
                Ps[w][hi * 4 + r][f * 16 + lo] = (f16)sf[f][r];
        // rescale O
#pragma unroll
        for (int n = 0; n < 4; ++n)
#pragma unroll
            for (int r = 0; r < 4; ++r) oacc[n][r] *= alpha[r];
        // O += P V
#pragma unroll
        for (int kk = 0; kk < 2; ++kk) {
            f16x8 pa = *(const f16x8*)(&Ps[w][lo][kk * 32 + hi * 8]);
#pragma unroll
            for (int n = 0; n < 4; ++n) {
                f16x8 vb = *(const f16x8*)(&Vs[n * 16 + lo][kk * 32 + hi * 8]);
                oacc[n] = __builtin_amdgcn_mfma_f32_16x16x32_f16(pa, vb, oacc[n], 0, 0, 0);
            }
        }
    }

    // epilogue: Oh[m][c] fp16, m = b*1024 + n, c = hh*64 + d
    f16* Op = Oh + ((size_t)b * SEQ + q0 + w * 16) * DIM + hh * HD;
#pragma unroll
    for (int r = 0; r < 4; ++r) {
        float inv = 1.f / l_run[r];
#pragma unroll
        for (int n = 0; n < 4; ++n)
            Op[(size_t)(hi * 4 + r) * DIM + n * 16 + lo] = (f16)(oacc[n][r] * inv);
    }
}

// ---------------------------------------------------------------------------
// Projection GEMM, fp16 MFMA: out[m,o] = sum_c Oh[m,c]*Wph[o,c] + bp[o].
// ---------------------------------------------------------------------------
__global__ __launch_bounds__(256) void proj_gemm_f16(
    const f16* __restrict__ Oh, const f16* __restrict__ Wph,
    const float* __restrict__ bp, float* __restrict__ out) {
    __shared__ f16 Asm[128][40];
    __shared__ f16 Bsm[128][40];
    const int tid = threadIdx.x;
    const int l = tid & 63, w = tid >> 6;
    const int lo = l & 15, hi = l >> 4;
    const int wm = w >> 1, wn = w & 1;
    const int m0 = blockIdx.y * 128, o0 = blockIdx.x * 128;

    f32x4 acc[4][4];
#pragma unroll
    for (int i = 0; i < 4; ++i)
#pragma unroll
        for (int j = 0; j < 4; ++j) { f32x4 z = {0.f, 0.f, 0.f, 0.f}; acc[i][j] = z; }

    const int rr = tid >> 1, cs = (tid & 1) * 16;
    for (int k0 = 0; k0 < DIM; k0 += 32) {
        __syncthreads();
        f16x8 av0 = *(const f16x8*)(Oh + (size_t)(m0 + rr) * DIM + k0 + cs);
        f16x8 av1 = *(const f16x8*)(Oh + (size_t)(m0 + rr) * DIM + k0 + cs + 8);
        f16x8 bv0 = *(const f16x8*)(Wph + (size_t)(o0 + rr) * DIM + k0 + cs);
        f16x8 bv1 = *(const f16x8*)(Wph + (size_t)(o0 + rr) * DIM + k0 + cs + 8);
        *(f16x8*)(&Asm[rr][cs])     = av0;
        *(f16x8*)(&Asm[rr][cs + 8]) = av1;
        *(f16x8*)(&Bsm[rr][cs])     = bv0;
        *(f16x8*)(&Bsm[rr][cs + 8]) = bv1;
        __syncthreads();
        f16x8 af[4], bf[4];
#pragma unroll
        for (int i = 0; i < 4; ++i)
            af[i] = *(const f16x8*)(&Asm[wm * 64 + i * 16 + lo][hi * 8]);
#pragma unroll
        for (int j = 0; j < 4; ++j)
            bf[j] = *(const f16x8*)(&Bsm[wn * 64 + j * 16 + lo][hi * 8]);
#pragma unroll
        for (int i = 0; i < 4; ++i)
#pragma unroll
            for (int j = 0; j < 4; ++j)
                acc[i][j] = __builtin_amdgcn_mfma_f32_16x16x32_f16(af[i], bf[j], acc[i][j], 0, 0, 0);
    }

    float bpv[4];
#pragma unroll
    for (int j = 0; j < 4; ++j) bpv[j] = bp[o0 + wn * 64 + j * 16 + lo];
#pragma unroll
    for (int i = 0; i < 4; ++i)
#pragma unroll
        for (int r = 0; r < 4; ++r) {
            const int m = m0 + wm * 64 + i * 16 + hi * 4 + r;
#pragma unroll
            for (int j = 0; j < 4; ++j)
                out[(size_t)m * DIM + o0 + wn * 64 + j * 16 + lo] = acc[i][j][r] + bpv[j];
        }
}

// ---------------------------------------------------------------------------
extern "C" void kernel_launch(void* const* d_in, const int* in_sizes, int n_in,
                              void* d_out, int out_size, void* d_ws, size_t ws_size,
                              hipStream_t stream) {
    const float* x      = (const float*)d_in[0];
    const void*  mask   = d_in[1];
    const float* w_qkv  = (const float*)d_in[2];
    const float* w_proj = (const float*)d_in[3];
    const float* b_proj = (const float*)d_in[4];
    float* out          = (float*)d_out;

    // workspace carve (all 16B-aligned)
    char* w = (char*)d_ws;
    int* mnorm = (int*)w;                  w += 16384;
    const size_t NX  = (size_t)NB * SEQ * DIM;      // 3,145,728
    const size_t NW1 = (size_t)3 * DIM * DIM;       // 1,769,472
    const size_t NW2 = (size_t)DIM * DIM;           //   589,824
    f16* Xh   = (f16*)w;  w += NX  * sizeof(f16);
    f16* W1h  = (f16*)w;  w += NW1 * sizeof(f16);
    f16* W2h  = (f16*)w;  w += NW2 * sizeof(f16);
    f16* Qh   = (f16*)w;  w += NX * sizeof(f16);
    f16* Kh   = (f16*)w;  w += NX * sizeof(f16);
    f16* Vth  = (f16*)w;  w += NX * sizeof(f16);
    f16* Oh   = (f16*)w;  w += NX * sizeof(f16);

    mask_norm_kernel<<<1, 256, 0, stream>>>(mask, mnorm);
    cvt_kernel<<<5376, 256, 0, stream>>>(x, w_qkv, w_proj, Xh, W1h, W2h);
    qkv_gemm_f16<<<dim3(18, 32), 256, 0, stream>>>(Xh, W1h, Qh, Kh, Vth);
    attn_f16<<<dim3(SEQ / 64, NB * NH), 256, 0, stream>>>(Qh, Kh, Vth, mnorm, Oh);
    proj_gemm_f16<<<dim3(6, 32), 256, 0, stream>>>(Oh, W2h, b_proj, out);
}

// Round 4
// 115.725 us; speedup vs baseline: 4.3951x; 1.1352x over previous
//
#include <hip/hip_runtime.h>
#include <hip/hip_fp16.h>
#include <float.h>

typedef _Float16 f16;
typedef __attribute__((ext_vector_type(4))) _Float16 f16x4;
typedef __attribute__((ext_vector_type(8))) _Float16 f16x8;
typedef __attribute__((ext_vector_type(4))) float f32x4;

#define NB 4
#define SEQ 1024
#define DIM 768
#define NH 12
#define HD 64
#define SCALE_F 0.125f

// direct global->LDS DMA, 16B per lane (dest = wave-uniform base + lane*16)
__device__ __forceinline__ void gload16(const f16* g, f16* lds) {
    __builtin_amdgcn_global_load_lds(
        (const __attribute__((address_space(1))) void*)g,
        (__attribute__((address_space(3))) void*)lds, 16, 0, 0);
}

// ---------------------------------------------------------------------------
// Mask normalization (verified): int32-or-uint8 autodetect.
// ---------------------------------------------------------------------------
__global__ void mask_norm_kernel(const void* __restrict__ mask_raw,
                                 int* __restrict__ mnorm) {
    __shared__ int is_u8;
    const int tid = threadIdx.x;
    if (tid == 0) is_u8 = 0;
    __syncthreads();
    const unsigned int* u32 = (const unsigned int*)mask_raw;
    int bad = 0;
    for (int i = tid; i < (NB * SEQ) / 4; i += blockDim.x)
        if (u32[i] > 1u) bad = 1;
    if (bad) atomicOr(&is_u8, 1);
    __syncthreads();
    const int u8mode = is_u8;
    const unsigned char* u8 = (const unsigned char*)mask_raw;
    const int* i32 = (const int*)mask_raw;
    for (int i = tid; i < NB * SEQ; i += blockDim.x)
        mnorm[i] = u8mode ? (u8[i] != 0) : (i32[i] != 0);
}

// ---------------------------------------------------------------------------
// fp32 -> fp16 convert for X, w_qkv, w_proj (one fused launch).
// ---------------------------------------------------------------------------
__global__ __launch_bounds__(256) void cvt_kernel(
    const float* __restrict__ X, const float* __restrict__ W1,
    const float* __restrict__ W2, f16* __restrict__ Xh,
    f16* __restrict__ W1h, f16* __restrict__ W2h) {
    const int A4 = (NB * SEQ * DIM) / 4;
    const int B4 = (3 * DIM * DIM) / 4;
    const int C4 = (DIM * DIM) / 4;
    int i = blockIdx.x * 256 + threadIdx.x;
    const float* s; f16* d; int j;
    if (i < A4)                { s = X;  d = Xh;  j = i; }
    else if (i < A4 + B4)      { s = W1; d = W1h; j = i - A4; }
    else if (i < A4 + B4 + C4) { s = W2; d = W2h; j = i - A4 - B4; }
    else return;
    float4 v = ((const float4*)s)[j];
    f16x4 h;
    h[0] = (f16)v.x; h[1] = (f16)v.y; h[2] = (f16)v.z; h[3] = (f16)v.w;
    *(f16x4*)(d + 4 * (size_t)j) = h;
}

// ---------------------------------------------------------------------------
// QKV GEMM, fp16 MFMA 16x16x32, global_load_lds staging (m97 structure).
// 128x128 tile, BK=32, 4 waves (2x2). Linear LDS [128][32].
// Epilogue: Q,K -> [bh][n][d]; V -> transposed [bh][d][n].
// ---------------------------------------------------------------------------
__global__ __launch_bounds__(256) void qkv_gemm_f16(
    const f16* __restrict__ Xh, const f16* __restrict__ Wh,
    f16* __restrict__ Qh, f16* __restrict__ Kh, f16* __restrict__ Vth) {
    __shared__ __align__(16) f16 Ah[128 * 32];
    __shared__ __align__(16) f16 Bh[128 * 32];
    const int tid = threadIdx.x;
    const int l = tid & 63, w = tid >> 6;
    const int lo = l & 15, hi = l >> 4;
    const int wm = w >> 1, wn = w & 1;
    const int m0 = blockIdx.y * 128, o0 = blockIdx.x * 128;

    f32x4 acc[4][4];
#pragma unroll
    for (int i = 0; i < 4; ++i)
#pragma unroll
        for (int j = 0; j < 4; ++j) { f32x4 z = {0.f, 0.f, 0.f, 0.f}; acc[i][j] = z; }

    // per-lane source coords for gload16: chunk = w*2+q covers 16 rows
    const int gr = l >> 2;            // row within chunk
    const int gc = (l & 3) * 8;       // f16 col within 32
    const f16* gA = Xh + (size_t)(m0 + w * 32 + gr) * DIM + gc;
    const f16* gB = Wh + (size_t)(o0 + w * 32 + gr) * DIM + gc;
    f16* lA = Ah + (w * 2) * 512;     // 512 f16 = 1KB per chunk
    f16* lB = Bh + (w * 2) * 512;

    for (int k0 = 0; k0 < DIM; k0 += 32) {
        __syncthreads();
        gload16(gA + k0,            lA);
        gload16(gA + k0 + 16 * DIM, lA + 512);
        gload16(gB + k0,            lB);
        gload16(gB + k0 + 16 * DIM, lB + 512);
        __syncthreads();
        f16x8 af[4], bf[4];
#pragma unroll
        for (int i = 0; i < 4; ++i)
            af[i] = *(const f16x8*)&Ah[(wm * 64 + i * 16 + lo) * 32 + hi * 8];
#pragma unroll
        for (int j = 0; j < 4; ++j)
            bf[j] = *(const f16x8*)&Bh[(wn * 64 + j * 16 + lo) * 32 + hi * 8];
#pragma unroll
        for (int i = 0; i < 4; ++i)
#pragma unroll
            for (int j = 0; j < 4; ++j)
                acc[i][j] = __builtin_amdgcn_mfma_f32_16x16x32_f16(af[i], bf[j], acc[i][j], 0, 0, 0);
    }

    // epilogue (verified round 3)
    const int oo = o0 + wn * 64;
    const int s = oo / DIM;
    const int hh = (oo % DIM) / HD;
    const int b = m0 >> 10;
    const int nbase = (m0 & 1023) + wm * 64;
    if (s < 2) {
        f16* dst = (s == 0) ? Qh : Kh;
        f16* base = dst + ((size_t)(b * NH + hh)) * SEQ * HD;
#pragma unroll
        for (int i = 0; i < 4; ++i)
#pragma unroll
            for (int r = 0; r < 4; ++r) {
                const int n = nbase + i * 16 + hi * 4 + r;
#pragma unroll
                for (int j = 0; j < 4; ++j)
                    base[(size_t)n * HD + j * 16 + lo] = (f16)acc[i][j][r];
            }
    } else {
        f16* base = Vth + ((size_t)(b * NH + hh)) * HD * SEQ;
#pragma unroll
        for (int i = 0; i < 4; ++i) {
            const int n4 = nbase + i * 16 + hi * 4;
#pragma unroll
            for (int j = 0; j < 4; ++j) {
                const int d = j * 16 + lo;
                f16x4 pv;
#pragma unroll
                for (int r = 0; r < 4; ++r) pv[r] = (f16)acc[i][j][r];
                *(f16x4*)(base + (size_t)d * SEQ + n4) = pv;
            }
        }
    }
}

// ---------------------------------------------------------------------------
// Flash attention, swapped-QK^T (S^T = mfma(K, Q)) so each lane owns ONE
// q-row: scalar online-softmax, 2 shuffles per reduce, vectorized P-store.
// XOR-swizzled LDS (row&7)<<4 on K/V/P. T14 async staging (load next tile
// into regs during compute). 4 waves, 64 q-rows/block, KVBLK=64.
// ---------------------------------------------------------------------------
__global__ __launch_bounds__(256) void attn_f16(
    const f16* __restrict__ Qh, const f16* __restrict__ Kh,
    const f16* __restrict__ Vth, const int* __restrict__ mnorm,
    f16* __restrict__ Oh) {
    const int bh = blockIdx.y, b = bh / NH, hh = bh % NH;
    const int q0 = blockIdx.x * 64;
    const int tid = threadIdx.x;
    const int l = tid & 63, w = tid >> 6;
    const int lo = l & 15, hi = l >> 4;

    __shared__ __align__(16) f16 Ks[64][72];     // [kv][d], cols XOR-swizzled
    __shared__ __align__(16) f16 Vs[64][72];     // [d][kv], cols XOR-swizzled
    __shared__ __align__(16) f16 Ps[4][16][72];  // per-wave [qr][kv], swizzled
    __shared__ int mks[64];

    const f16* Qp = Qh + (size_t)bh * SEQ * HD;
    const f16* Kp = Kh + (size_t)bh * SEQ * HD;
    const f16* Vp = Vth + (size_t)bh * HD * SEQ;

    // Q B-fragments (col = q-row = lo, k = d)
    f16x8 qa[2];
#pragma unroll
    for (int kk = 0; kk < 2; ++kk)
        qa[kk] = *(const f16x8*)(Qp + (size_t)(q0 + w * 16 + lo) * HD + kk * 32 + hi * 8);
    const int mq = mnorm[b * SEQ + q0 + w * 16 + lo];

    float m_run = -FLT_MAX, l_run = 0.f;
    f32x4 oacc[4];
#pragma unroll
    for (int n = 0; n < 4; ++n) { f32x4 z = {0.f, 0.f, 0.f, 0.f}; oacc[n] = z; }

    // staging coords: 64 rows x 64 cols, 4 lanes/row, 16 cols each
    const int sr = tid >> 2, sc = (tid & 3) * 16;
    const int swz = (sr & 7) * 8;        // f16-index XOR for row sr
    const int s8 = (lo & 7) * 8;         // XOR for frag-read rows (row%8 == lo%8)

    f16x8 kr0, kr1, vr0, vr1; int mkr;
    // prologue: load tile 0
    kr0 = *(const f16x8*)(Kp + (size_t)sr * HD + sc);
    kr1 = *(const f16x8*)(Kp + (size_t)sr * HD + sc + 8);
    vr0 = *(const f16x8*)(Vp + (size_t)sr * SEQ + sc);
    vr1 = *(const f16x8*)(Vp + (size_t)sr * SEQ + sc + 8);
    mkr = mnorm[b * SEQ + l];

    for (int t = 0; t < 16; ++t) {
        __syncthreads();
        *(f16x8*)&Ks[sr][sc ^ swz]       = kr0;
        *(f16x8*)&Ks[sr][(sc + 8) ^ swz] = kr1;
        *(f16x8*)&Vs[sr][sc ^ swz]       = vr0;
        *(f16x8*)&Vs[sr][(sc + 8) ^ swz] = vr1;
        if (tid < 64) mks[tid] = mkr;
        __syncthreads();
        if (t < 15) {   // T14: issue next tile's loads; consumed next iter
            const int kv1 = (t + 1) * 64;
            kr0 = *(const f16x8*)(Kp + (size_t)(kv1 + sr) * HD + sc);
            kr1 = *(const f16x8*)(Kp + (size_t)(kv1 + sr) * HD + sc + 8);
            vr0 = *(const f16x8*)(Vp + (size_t)sr * SEQ + kv1 + sc);
            vr1 = *(const f16x8*)(Vp + (size_t)sr * SEQ + kv1 + sc + 8);
            mkr = mnorm[b * SEQ + kv1 + l];
        }

        // S^T = K Q^T : frag f -> kv rows f*16..f*16+15; sf[f][r] is
        // S[q-row = lo][kv = f*16 + hi*4 + r]
        f32x4 sf[4];
#pragma unroll
        for (int f = 0; f < 4; ++f) { f32x4 z = {0.f, 0.f, 0.f, 0.f}; sf[f] = z; }
#pragma unroll
        for (int kk = 0; kk < 2; ++kk)
#pragma unroll
            for (int f = 0; f < 4; ++f) {
                f16x8 kf = *(const f16x8*)&Ks[f * 16 + lo][(kk * 32 + hi * 8) ^ s8];
                sf[f] = __builtin_amdgcn_mfma_f32_16x16x32_f16(kf, qa[kk], sf[f], 0, 0, 0);
            }
        // scale + mask
#pragma unroll
        for (int f = 0; f < 4; ++f) {
            int mv[4];
            *(int4*)mv = *(const int4*)&mks[f * 16 + hi * 4];
#pragma unroll
            for (int r = 0; r < 4; ++r)
                sf[f][r] = (mq && mv[r]) ? sf[f][r] * SCALE_F : -FLT_MAX;
        }
        // scalar online softmax for this lane's q-row
        float pm = -FLT_MAX;
#pragma unroll
        for (int f = 0; f < 4; ++f)
            pm = fmaxf(pm, fmaxf(fmaxf(sf[f][0], sf[f][1]), fmaxf(sf[f][2], sf[f][3])));
        pm = fmaxf(pm, __shfl_xor(pm, 16));
        pm = fmaxf(pm, __shfl_xor(pm, 32));
        const float mn = fmaxf(m_run, pm);
        const float alpha = __expf(m_run - mn);
        m_run = mn;
        float rs = 0.f;
#pragma unroll
        for (int f = 0; f < 4; ++f)
#pragma unroll
            for (int r = 0; r < 4; ++r) {
                float p = __expf(sf[f][r] - mn);
                sf[f][r] = p;
                rs += p;
            }
        rs += __shfl_xor(rs, 16);
        rs += __shfl_xor(rs, 32);
        l_run = l_run * alpha + rs;

        // P-store: 4 contiguous kv values per frag -> ds_write_b64
#pragma unroll
        for (int f = 0; f < 4; ++f) {
            f16x4 pv;
#pragma unroll
            for (int r = 0; r < 4; ++r) pv[r] = (f16)sf[f][r];
            *(f16x4*)&Ps[w][lo][(f * 16 + hi * 4) ^ s8] = pv;
        }
        // rescale O (row of oacc = q-row hi*4+r -> fetch that row's alpha)
        float ar[4];
#pragma unroll
        for (int r = 0; r < 4; ++r) ar[r] = __shfl(alpha, hi * 4 + r);
#pragma unroll
        for (int n = 0; n < 4; ++n)
#pragma unroll
            for (int r = 0; r < 4; ++r) oacc[n][r] *= ar[r];
        // O += P V
#pragma unroll
        for (int kk = 0; kk < 2; ++kk) {
            f16x8 pa = *(const f16x8*)&Ps[w][lo][(kk * 32 + hi * 8) ^ s8];
#pragma unroll
            for (int n = 0; n < 4; ++n) {
                f16x8 vb = *(const f16x8*)&Vs[n * 16 + lo][(kk * 32 + hi * 8) ^ s8];
                oacc[n] = __builtin_amdgcn_mfma_f32_16x16x32_f16(pa, vb, oacc[n], 0, 0, 0);
            }
        }
    }

    // epilogue: row hi*4+r of this wave's 16 q-rows; that row's l_run
    float il[4];
#pragma unroll
    for (int r = 0; r < 4; ++r) il[r] = __shfl(l_run, hi * 4 + r);
    f16* Op = Oh + ((size_t)b * SEQ + q0 + w * 16) * DIM + hh * HD;
#pragma unroll
    for (int r = 0; r < 4; ++r) {
        const float inv = 1.f / il[r];
#pragma unroll
        for (int n = 0; n < 4; ++n)
            Op[(size_t)(hi * 4 + r) * DIM + n * 16 + lo] = (f16)(oacc[n][r] * inv);
    }
}

// ---------------------------------------------------------------------------
// Projection GEMM, fp16 MFMA, global_load_lds staging.
// ---------------------------------------------------------------------------
__global__ __launch_bounds__(256) void proj_gemm_f16(
    const f16* __restrict__ Oh, const f16* __restrict__ Wph,
    const float* __restrict__ bp, float* __restrict__ out) {
    __shared__ __align__(16) f16 Ah[128 * 32];
    __shared__ __align__(16) f16 Bh[128 * 32];
    const int tid = threadIdx.x;
    const int l = tid & 63, w = tid >> 6;
    const int lo = l & 15, hi = l >> 4;
    const int wm = w >> 1, wn = w & 1;
    const int m0 = blockIdx.y * 128, o0 = blockIdx.x * 128;

    f32x4 acc[4][4];
#pragma unroll
    for (int i = 0; i < 4; ++i)
#pragma unroll
        for (int j = 0; j < 4; ++j) { f32x4 z = {0.f, 0.f, 0.f, 0.f}; acc[i][j] = z; }

    const int gr = l >> 2;
    const int gc = (l & 3) * 8;
    const f16* gA = Oh + (size_t)(m0 + w * 32 + gr) * DIM + gc;
    const f16* gB = Wph + (size_t)(o0 + w * 32 + gr) * DIM + gc;
    f16* lA = Ah + (w * 2) * 512;
    f16* lB = Bh + (w * 2) * 512;

    for (int k0 = 0; k0 < DIM; k0 += 32) {
        __syncthreads();
        gload16(gA + k0,            lA);
        gload16(gA + k0 + 16 * DIM, lA + 512);
        gload16(gB + k0,            lB);
        gload16(gB + k0 + 16 * DIM, lB + 512);
        __syncthreads();
        f16x8 af[4], bf[4];
#pragma unroll
        for (int i = 0; i < 4; ++i)
            af[i] = *(const f16x8*)&Ah[(wm * 64 + i * 16 + lo) * 32 + hi * 8];
#pragma unroll
        for (int j = 0; j < 4; ++j)
            bf[j] = *(const f16x8*)&Bh[(wn * 64 + j * 16 + lo) * 32 + hi * 8];
#pragma unroll
        for (int i = 0; i < 4; ++i)
#pragma unroll
            for (int j = 0; j < 4; ++j)
                acc[i][j] = __builtin_amdgcn_mfma_f32_16x16x32_f16(af[i], bf[j], acc[i][j], 0, 0, 0);
    }

    float bpv[4];
#pragma unroll
    for (int j = 0; j < 4; ++j) bpv[j] = bp[o0 + wn * 64 + j * 16 + lo];
#pragma unroll
    for (int i = 0; i < 4; ++i)
#pragma unroll
        for (int r = 0; r < 4; ++r) {
            const int m = m0 + wm * 64 + i * 16 + hi * 4 + r;
#pragma unroll
            for (int j = 0; j < 4; ++j)
                out[(size_t)m * DIM + o0 + wn * 64 + j * 16 + lo] = acc[i][j][r] + bpv[j];
        }
}

// ---------------------------------------------------------------------------
extern "C" void kernel_launch(void* const* d_in, const int* in_sizes, int n_in,
                              void* d_out, int out_size, void* d_ws, size_t ws_size,
                              hipStream_t stream) {
    const float* x      = (const float*)d_in[0];
    const void*  mask   = d_in[1];
    const float* w_qkv  = (const float*)d_in[2];
    const float* w_proj = (const float*)d_in[3];
    const float* b_proj = (const float*)d_in[4];
    float* out          = (float*)d_out;

    char* w = (char*)d_ws;
    int* mnorm = (int*)w;                  w += 16384;
    const size_t NX  = (size_t)NB * SEQ * DIM;
    const size_t NW1 = (size_t)3 * DIM * DIM;
    const size_t NW2 = (size_t)DIM * DIM;
    f16* Xh   = (f16*)w;  w += NX  * sizeof(f16);
    f16* W1h  = (f16*)w;  w += NW1 * sizeof(f16);
    f16* W2h  = (f16*)w;  w += NW2 * sizeof(f16);
    f16* Qh   = (f16*)w;  w += NX * sizeof(f16);
    f16* Kh   = (f16*)w;  w += NX * sizeof(f16);
    f16* Vth  = (f16*)w;  w += NX * sizeof(f16);
    f16* Oh   = (f16*)w;  w += NX * sizeof(f16);

    mask_norm_kernel<<<1, 256, 0, stream>>>(mask, mnorm);
    cvt_kernel<<<5376, 256, 0, stream>>>(x, w_qkv, w_proj, Xh, W1h, W2h);
    qkv_gemm_f16<<<dim3(18, 32), 256, 0, stream>>>(Xh, W1h, Qh, Kh, Vth);
    attn_f16<<<dim3(SEQ / 64, NB * NH), 256, 0, stream>>>(Qh, Kh, Vth, mnorm, Oh);
    proj_gemm_f16<<<dim3(6, 32), 256, 0, stream>>>(Oh, W2h, b_proj, out);
}